// Round 3
// baseline (413.184 us; speedup 1.0000x reference)
//
#include <hip/hip_runtime.h>

#define N_ROWS 4096
#define DIM 1024
#define INV_T (1.0f / 0.07f)
#define FP8_SCALE 16.0f
// acc = (16*c1)·(16*c2) = 256*cos; exp2 argument = acc * INV_T * log2(e) / 256
#define EXP_SCALE (INV_T * 1.44269504088896f / 256.0f)
#define BK 128   // fp8 elements per k-tile (= 128 B rows in LDS) = one MFMA-K
#define NJT 16   // number of j-tiles (= grid.x of gemm, 256-wide tiles)

typedef __attribute__((ext_vector_type(4))) float floatx4;
typedef __attribute__((ext_vector_type(4))) int int4x;
typedef __attribute__((ext_vector_type(8))) int int8x;

// fp32 -> OCP e4m3fn. Prefer the HW packed convert (v_cvt_pk_fp8_f32, RNE).
#if __has_builtin(__builtin_amdgcn_cvt_pk_fp8_f32)
__device__ inline unsigned int pack4_e4m3(float x, float y, float z, float w) {
    int p = __builtin_amdgcn_cvt_pk_fp8_f32(x, y, 0, false);   // low word
    p = __builtin_amdgcn_cvt_pk_fp8_f32(z, w, p, true);        // high word
    return (unsigned int)p;
}
#else
__device__ inline unsigned int f2e4m3(float x) {
    unsigned int u = __float_as_uint(x);
    unsigned int s = (u >> 24) & 0x80u;
    int e = (int)((u >> 23) & 0xffu);
    unsigned int m = u & 0x7fffffu;
    if (e < 121) return s;              // FTZ (|x| < 2^-6)
    unsigned int t = m >> 20;
    unsigned int rest = m & 0xFFFFFu;
    t += (rest > 0x80000u) || (rest == 0x80000u && (t & 1u));  // RNE
    int e8 = e - 120;
    if (t == 8u) { t = 0u; e8 += 1; }
    return s | ((unsigned int)e8 << 3) | t;
}
__device__ inline unsigned int pack4_e4m3(float x, float y, float z, float w) {
    return f2e4m3(x) | (f2e4m3(y) << 8) | (f2e4m3(z) << 16) | (f2e4m3(w) << 24);
}
#endif

// One WAVE per row (4 rows / 256-thread block). Emits fp8 normalized rows
// (scaled by 16) + exact fp32 diagonal logit. Block 0 zeroes out[0].
__global__ __launch_bounds__(256) void k_normalize(
    const float* __restrict__ z1, const float* __restrict__ z2,
    unsigned char* __restrict__ z1f, unsigned char* __restrict__ z2f,
    float* __restrict__ diag, float* __restrict__ out) {
    const int lane = threadIdx.x & 63, wave = threadIdx.x >> 6;
    const int row = blockIdx.x * 4 + wave;

    if (blockIdx.x == 0 && threadIdx.x == 0) out[0] = 0.f;

    const float4* A = reinterpret_cast<const float4*>(z1 + (size_t)row * DIM);
    const float4* B = reinterpret_cast<const float4*>(z2 + (size_t)row * DIM);
    float4 a[4], b[4];
    #pragma unroll
    for (int rep = 0; rep < 4; ++rep) {
        a[rep] = A[lane + 64 * rep];
        b[rep] = B[lane + 64 * rep];
    }

    float s11 = 0.f, s22 = 0.f, s12 = 0.f;
    #pragma unroll
    for (int rep = 0; rep < 4; ++rep) {
        s11 += a[rep].x * a[rep].x + a[rep].y * a[rep].y
             + a[rep].z * a[rep].z + a[rep].w * a[rep].w;
        s22 += b[rep].x * b[rep].x + b[rep].y * b[rep].y
             + b[rep].z * b[rep].z + b[rep].w * b[rep].w;
        s12 += a[rep].x * b[rep].x + a[rep].y * b[rep].y
             + a[rep].z * b[rep].z + a[rep].w * b[rep].w;
    }
    #pragma unroll
    for (int m = 32; m >= 1; m >>= 1) {
        s11 += __shfl_xor(s11, m, 64);
        s22 += __shfl_xor(s22, m, 64);
        s12 += __shfl_xor(s12, m, 64);
    }

    const float n1 = fmaxf(sqrtf(s11), 1e-12f);
    const float n2 = fmaxf(sqrtf(s22), 1e-12f);
    if (lane == 0) diag[row] = s12 / (n1 * n2) * INV_T;
    const float i1 = FP8_SCALE / n1, i2 = FP8_SCALE / n2;

    unsigned int* O1 = reinterpret_cast<unsigned int*>(z1f + (size_t)row * DIM);
    unsigned int* O2 = reinterpret_cast<unsigned int*>(z2f + (size_t)row * DIM);
    #pragma unroll
    for (int rep = 0; rep < 4; ++rep) {
        O1[lane + 64 * rep] = pack4_e4m3(a[rep].x * i1, a[rep].y * i1,
                                         a[rep].z * i1, a[rep].w * i1);
        O2[lane + 64 * rep] = pack4_e4m3(b[rep].x * i2, b[rep].y * i2,
                                         b[rep].z * i2, b[rep].w * i2);
    }
}

// swizzle-corrected fragment read: lane reads 32 k-bytes [q*32, +32) of row.
__device__ __forceinline__ int8x ldfrag(const unsigned char* base, int row, int q) {
    const int rs = row & 7;
    const unsigned char* rp = base + row * BK;
    int4x lo = *reinterpret_cast<const int4x*>(rp + (((2 * q) ^ rs) * 16));
    int4x hi = *reinterpret_cast<const int4x*>(rp + (((2 * q + 1) ^ rs) * 16));
    return __builtin_shufflevector(lo, hi, 0, 1, 2, 3, 4, 5, 6, 7);
}

#define MFMA_SC(a, b, c) \
    __builtin_amdgcn_mfma_scale_f32_16x16x128_f8f6f4( \
        (a), (b), (c), 0 /*fmt A*/, 0 /*fmt B*/, 0, 0x7F, 0, 0x7F)

// 256x256 8-phase MX-fp8 GEMM (T2 swizzle + T3/T4 counted-vmcnt + T5 setprio).
// 512 threads = 8 waves (2M x 4N). Phase quadrant (mh,nh) reads ONLY A-half
// mh and B-half nh, so each phase frees one A-half + one B-half for restage.
// Region issue schedule: A0(c)@phase 4c-6, B0@4c-5, A1@4c-4, B1@4c-3.
// One s_waitcnt vmcnt(4) per K-tile (phases 4 & 8); vmcnt(0) only in the
// final iteration (trailing issues skipped).
//
// R2 post-mortem: identical counters across launch_bounds (512,2)/(512,1)
// => the 128-VGPR count was demand, not a cap: the floatx4 acc[2][4][2][2]
// ALLOCA was never promoted — every MFMA read/wrote C/D in scratch
// (8 mfma x 32 B x 512 thr x 32 phases x 256 blk = 537 MB/dir, matching
// FETCH 483 / WRITE 586 MB). Fix: NO accumulator array — 32 individually
// named floatx4 SSA values via token-pasted macros; epilogue fully
// macro-expanded (every vector index a literal). "memory" clobbers cannot
// touch SSA values.
__global__ __launch_bounds__(512, 1) void k_gemm_sumexp(
    const unsigned char* __restrict__ z1f, const unsigned char* __restrict__ z2f,
    float* __restrict__ P) {
    __shared__ __attribute__((aligned(16))) unsigned char As[2][256 * BK]; // 64 KB
    __shared__ __attribute__((aligned(16))) unsigned char Bs[2][256 * BK]; // 64 KB

    const int iT = blockIdx.y, jT = blockIdx.x;
    const int tid = threadIdx.x;
    const int lane = tid & 63, wave = tid >> 6;   // 8 waves
    const int wm = wave >> 2, wn = wave & 3;      // 2 (M) x 4 (N)
    const int ml = lane & 15, q = lane >> 4;      // MFMA lane decomposition
    const int i0 = iT * 256, j0 = jT * 256;

    // staging geometry: one wave-issue = 1 KB = 8 rows x 8 16B-chunks.
    // LDS slot s of row r holds global chunk s ^ (r&7)  (T2 swizzle).
    const int srow = lane >> 3;
    const int sg = ((lane & 7) ^ srow) * 16;

// 32 named accumulators: c<MH><T><NH><N>, each a floatx4 (4 C-rows).
#define ACC(MH, T, NH, N) c##MH##T##NH##N
#define Z4 ((floatx4){0.f, 0.f, 0.f, 0.f})
#define DECL4(MH, T)                                                           \
    floatx4 ACC(MH, T, 0, 0) = Z4, ACC(MH, T, 0, 1) = Z4,                      \
            ACC(MH, T, 1, 0) = Z4, ACC(MH, T, 1, 1) = Z4
    DECL4(0, 0); DECL4(0, 1); DECL4(0, 2); DECL4(0, 3);
    DECL4(1, 0); DECL4(1, 1); DECL4(1, 2); DECL4(1, 3);

// stage one 128-row region (RB = 0|128) of K-tile TL into buffer DB:
// 2 issues/thread, wave-uniform linear LDS dest, pre-swizzled global src.
#define STA(RB, TL, DB) do {                                                   \
    const unsigned char* g0_ =                                                 \
        z1f + (size_t)(i0 + (RB) + wave * 16 + srow) * DIM + (TL) * BK + sg;   \
    __builtin_amdgcn_global_load_lds(                                          \
        (const __attribute__((address_space(1))) void*)g0_,                    \
        (__attribute__((address_space(3))) void*)(&As[DB][((RB) + wave * 16) * BK]), \
        16, 0, 0);                                                             \
    __builtin_amdgcn_global_load_lds(                                          \
        (const __attribute__((address_space(1))) void*)(g0_ + (size_t)8 * DIM),\
        (__attribute__((address_space(3))) void*)(&As[DB][((RB) + wave * 16 + 8) * BK]), \
        16, 0, 0);                                                             \
} while (0)

#define STB(RB, TL, DB) do {                                                   \
    const unsigned char* g0_ =                                                 \
        z2f + (size_t)(j0 + (RB) + wave * 16 + srow) * DIM + (TL) * BK + sg;   \
    __builtin_amdgcn_global_load_lds(                                          \
        (const __attribute__((address_space(1))) void*)g0_,                    \
        (__attribute__((address_space(3))) void*)(&Bs[DB][((RB) + wave * 16) * BK]), \
        16, 0, 0);                                                             \
    __builtin_amdgcn_global_load_lds(                                          \
        (const __attribute__((address_space(1))) void*)(g0_ + (size_t)8 * DIM),\
        (__attribute__((address_space(3))) void*)(&Bs[DB][((RB) + wave * 16 + 8) * BK]), \
        16, 0, 0);                                                             \
} while (0)

// one phase: ds_read quadrant frags | STAGE | barrier | lgkmcnt(0) |
// setprio(1) 8x MFMA setprio(0) | GATE | barrier
#define PHASE(BUF, MH, NH, STAGE, GATE) do {                                   \
    int8x af0_ = ldfrag(&As[BUF][0], (MH) * 128 + wm * 64 +  0 + ml, q);       \
    int8x af1_ = ldfrag(&As[BUF][0], (MH) * 128 + wm * 64 + 16 + ml, q);       \
    int8x af2_ = ldfrag(&As[BUF][0], (MH) * 128 + wm * 64 + 32 + ml, q);       \
    int8x af3_ = ldfrag(&As[BUF][0], (MH) * 128 + wm * 64 + 48 + ml, q);       \
    int8x bf0_ = ldfrag(&Bs[BUF][0], (NH) * 128 + wn * 32 +  0 + ml, q);       \
    int8x bf1_ = ldfrag(&Bs[BUF][0], (NH) * 128 + wn * 32 + 16 + ml, q);       \
    STAGE;                                                                     \
    __builtin_amdgcn_s_barrier();                                              \
    asm volatile("s_waitcnt lgkmcnt(0)" ::: "memory");                         \
    __builtin_amdgcn_s_setprio(1);                                             \
    ACC(MH, 0, NH, 0) = MFMA_SC(af0_, bf0_, ACC(MH, 0, NH, 0));                \
    ACC(MH, 0, NH, 1) = MFMA_SC(af0_, bf1_, ACC(MH, 0, NH, 1));                \
    ACC(MH, 1, NH, 0) = MFMA_SC(af1_, bf0_, ACC(MH, 1, NH, 0));                \
    ACC(MH, 1, NH, 1) = MFMA_SC(af1_, bf1_, ACC(MH, 1, NH, 1));                \
    ACC(MH, 2, NH, 0) = MFMA_SC(af2_, bf0_, ACC(MH, 2, NH, 0));                \
    ACC(MH, 2, NH, 1) = MFMA_SC(af2_, bf1_, ACC(MH, 2, NH, 1));                \
    ACC(MH, 3, NH, 0) = MFMA_SC(af3_, bf0_, ACC(MH, 3, NH, 0));                \
    ACC(MH, 3, NH, 1) = MFMA_SC(af3_, bf1_, ACC(MH, 3, NH, 1));                \
    __builtin_amdgcn_s_setprio(0);                                             \
    GATE;                                                                      \
    __builtin_amdgcn_s_barrier();                                              \
} while (0)

    // prologue: tile0 {A0,B0,A1,B1} + tile1 {A0,B0}; allow tile1's 4 loads
    // in flight while guaranteeing tile0 landed.
    STA(0, 0, 0);   STB(0, 0, 0);
    STA(128, 0, 0); STB(128, 0, 0);
    STA(0, 1, 1);   STB(0, 1, 1);
    asm volatile("s_waitcnt vmcnt(4)" ::: "memory");
    __builtin_amdgcn_s_barrier();

    // 8 K-tiles, 2 per iteration (even -> buf0, odd -> buf1).
    #pragma unroll
    for (int t = 0; t < 4; ++t) {
        PHASE(0, 0, 0, STA(128, 2 * t + 1, 1), (void)0);
        PHASE(0, 0, 1, STB(128, 2 * t + 1, 1), (void)0);
        PHASE(0, 1, 0, if (t < 3) STA(0, 2 * t + 2, 0), (void)0);
        PHASE(0, 1, 1, if (t < 3) STB(0, 2 * t + 2, 0),
              if (t < 3) { asm volatile("s_waitcnt vmcnt(4)" ::: "memory"); }
              else       { asm volatile("s_waitcnt vmcnt(0)" ::: "memory"); });
        PHASE(1, 0, 0, if (t < 3) STA(128, 2 * t + 2, 0), (void)0);
        PHASE(1, 0, 1, if (t < 3) STB(128, 2 * t + 2, 0), (void)0);
        PHASE(1, 1, 0, if (t < 3) STA(0, 2 * t + 3, 1), (void)0);
        PHASE(1, 1, 1, if (t < 3) STB(0, 2 * t + 3, 1),
              if (t < 3) { asm volatile("s_waitcnt vmcnt(4)" ::: "memory"); }
              else       { asm volatile("s_waitcnt vmcnt(0)" ::: "memory"); });
    }

    // Epilogue. C/D: col = ml, row-in-16 = q*4+r. Global row =
    // mh*128 + wm*64 + t*16 + q*4 + r; cols covered by (nh,n,ml) = 64/wave.
    // exp + sum over (nh,n), butterfly over 16 ml-lanes, combine the 4
    // wn-waves via LDS, one store per row. Fully macro-expanded: every
    // vector index is a literal (no dynamic ext_vector indexing).
    float* Pl = reinterpret_cast<float*>(&As[0][0]);  // 4 x 256 floats
#define EPIR(MH, T, R) do {                                                    \
    float v_ = __builtin_amdgcn_exp2f(ACC(MH, T, 0, 0)[R] * EXP_SCALE)         \
             + __builtin_amdgcn_exp2f(ACC(MH, T, 0, 1)[R] * EXP_SCALE)         \
             + __builtin_amdgcn_exp2f(ACC(MH, T, 1, 0)[R] * EXP_SCALE)         \
             + __builtin_amdgcn_exp2f(ACC(MH, T, 1, 1)[R] * EXP_SCALE);        \
    v_ += __shfl_xor(v_, 1, 64);                                               \
    v_ += __shfl_xor(v_, 2, 64);                                               \
    v_ += __shfl_xor(v_, 4, 64);                                               \
    v_ += __shfl_xor(v_, 8, 64);                                               \
    if (ml == 0)                                                               \
        Pl[wn * 256 + (MH) * 128 + wm * 64 + (T) * 16 + q * 4 + (R)] = v_;     \
} while (0)
#define EPI(MH, T) EPIR(MH, T, 0); EPIR(MH, T, 1); EPIR(MH, T, 2); EPIR(MH, T, 3)
    EPI(0, 0); EPI(0, 1); EPI(0, 2); EPI(0, 3);
    EPI(1, 0); EPI(1, 1); EPI(1, 2); EPI(1, 3);
    __syncthreads();
    if (tid < 256) {
        float s = Pl[tid] + Pl[256 + tid] + Pl[512 + tid] + Pl[768 + tid];
        P[jT * N_ROWS + i0 + tid] = s;
    }
}

// 32 blocks x 128 threads: one row per thread, coalesced P reads,
// block partial-sum -> atomicAdd into out[0] (zeroed by k_normalize).
__global__ __launch_bounds__(128) void k_finalize(
    const float* __restrict__ P, const float* __restrict__ diag,
    float* __restrict__ out) {
    const int t = threadIdx.x;
    const int i = blockIdx.x * 128 + t;
    float s = 0.f;
    #pragma unroll
    for (int jt = 0; jt < NJT; ++jt)
        s += P[jt * N_ROWS + i];
    float v = logf(s) - diag[i];
    #pragma unroll
    for (int m = 32; m >= 1; m >>= 1)
        v += __shfl_xor(v, m, 64);
    __shared__ float r[2];
    if ((t & 63) == 0) r[t >> 6] = v;
    __syncthreads();
    if (t == 0) atomicAdd(out, (r[0] + r[1]) * (1.0f / N_ROWS));
}

extern "C" void kernel_launch(void* const* d_in, const int* in_sizes, int n_in,
                              void* d_out, int out_size, void* d_ws, size_t ws_size,
                              hipStream_t stream) {
    const float* z1 = (const float*)d_in[0];
    const float* z2 = (const float*)d_in[1];

    char* ws = (char*)d_ws;
    unsigned char* z1f = (unsigned char*)ws;                                     // 4 MB
    unsigned char* z2f = (unsigned char*)(ws + (size_t)N_ROWS * DIM);            // 4 MB
    float* diag = (float*)(ws + (size_t)N_ROWS * DIM * 2);                       // 16 KB
    float* P = diag + N_ROWS;                                                    // 256 KB

    k_normalize<<<N_ROWS / 4, 256, 0, stream>>>(z1, z2, z1f, z2f, diag,
                                                (float*)d_out);
    k_gemm_sumexp<<<dim3(NJT, 16), 512, 0, stream>>>(z1f, z2f, P);
    k_finalize<<<32, 128, 0, stream>>>(P, diag, (float*)d_out);
}

// Round 4
// 99.481 us; speedup vs baseline: 4.1534x; 4.1534x over previous
//
#include <hip/hip_runtime.h>

#define N_ROWS 4096
#define DIM 1024
#define INV_T (1.0f / 0.07f)
#define FP8_SCALE 16.0f
// acc = (16*c1)·(16*c2) = 256*cos; exp2 argument = acc * INV_T * log2(e) / 256
#define EXP_SCALE (INV_T * 1.44269504088896f / 256.0f)
#define BK 128   // fp8 elements per k-tile (= 128 B rows in LDS) = one MFMA-K
#define NJT 32   // number of j-tiles (= grid.x of gemm)

typedef __attribute__((ext_vector_type(4))) float floatx4;
typedef __attribute__((ext_vector_type(4))) int int4x;
typedef __attribute__((ext_vector_type(8))) int int8x;

// fp32 -> OCP e4m3fn. Prefer the HW packed convert (v_cvt_pk_fp8_f32, RNE).
#if __has_builtin(__builtin_amdgcn_cvt_pk_fp8_f32)
__device__ inline unsigned int pack4_e4m3(float x, float y, float z, float w) {
    int p = __builtin_amdgcn_cvt_pk_fp8_f32(x, y, 0, false);   // low word
    p = __builtin_amdgcn_cvt_pk_fp8_f32(z, w, p, true);        // high word
    return (unsigned int)p;
}
#else
__device__ inline unsigned int f2e4m3(float x) {
    unsigned int u = __float_as_uint(x);
    unsigned int s = (u >> 24) & 0x80u;
    int e = (int)((u >> 23) & 0xffu);
    unsigned int m = u & 0x7fffffu;
    if (e < 121) return s;              // FTZ (|x| < 2^-6)
    unsigned int t = m >> 20;
    unsigned int rest = m & 0xFFFFFu;
    t += (rest > 0x80000u) || (rest == 0x80000u && (t & 1u));  // RNE
    int e8 = e - 120;
    if (t == 8u) { t = 0u; e8 += 1; }
    return s | ((unsigned int)e8 << 3) | t;
}
__device__ inline unsigned int pack4_e4m3(float x, float y, float z, float w) {
    return f2e4m3(x) | (f2e4m3(y) << 8) | (f2e4m3(z) << 16) | (f2e4m3(w) << 24);
}
#endif

// One WAVE per row (4 rows / 256-thread block). Emits fp8 normalized rows
// (scaled by 16) + exact fp32 diagonal logit. Block 0 zeroes out[0].
__global__ __launch_bounds__(256) void k_normalize(
    const float* __restrict__ z1, const float* __restrict__ z2,
    unsigned char* __restrict__ z1f, unsigned char* __restrict__ z2f,
    float* __restrict__ diag, float* __restrict__ out) {
    const int lane = threadIdx.x & 63, wave = threadIdx.x >> 6;
    const int row = blockIdx.x * 4 + wave;

    if (blockIdx.x == 0 && threadIdx.x == 0) out[0] = 0.f;

    const float4* A = reinterpret_cast<const float4*>(z1 + (size_t)row * DIM);
    const float4* B = reinterpret_cast<const float4*>(z2 + (size_t)row * DIM);
    float4 a[4], b[4];
    #pragma unroll
    for (int rep = 0; rep < 4; ++rep) {
        a[rep] = A[lane + 64 * rep];
        b[rep] = B[lane + 64 * rep];
    }

    float s11 = 0.f, s22 = 0.f, s12 = 0.f;
    #pragma unroll
    for (int rep = 0; rep < 4; ++rep) {
        s11 += a[rep].x * a[rep].x + a[rep].y * a[rep].y
             + a[rep].z * a[rep].z + a[rep].w * a[rep].w;
        s22 += b[rep].x * b[rep].x + b[rep].y * b[rep].y
             + b[rep].z * b[rep].z + b[rep].w * b[rep].w;
        s12 += a[rep].x * b[rep].x + a[rep].y * b[rep].y
             + a[rep].z * b[rep].z + a[rep].w * b[rep].w;
    }
    #pragma unroll
    for (int m = 32; m >= 1; m >>= 1) {
        s11 += __shfl_xor(s11, m, 64);
        s22 += __shfl_xor(s22, m, 64);
        s12 += __shfl_xor(s12, m, 64);
    }

    const float n1 = fmaxf(sqrtf(s11), 1e-12f);
    const float n2 = fmaxf(sqrtf(s22), 1e-12f);
    if (lane == 0) diag[row] = s12 / (n1 * n2) * INV_T;
    const float i1 = FP8_SCALE / n1, i2 = FP8_SCALE / n2;

    unsigned int* O1 = reinterpret_cast<unsigned int*>(z1f + (size_t)row * DIM);
    unsigned int* O2 = reinterpret_cast<unsigned int*>(z2f + (size_t)row * DIM);
    #pragma unroll
    for (int rep = 0; rep < 4; ++rep) {
        O1[lane + 64 * rep] = pack4_e4m3(a[rep].x * i1, a[rep].y * i1,
                                         a[rep].z * i1, a[rep].w * i1);
        O2[lane + 64 * rep] = pack4_e4m3(b[rep].x * i2, b[rep].y * i2,
                                         b[rep].z * i2, b[rep].w * i2);
    }
}

// MX-scaled fp8 GEMM, R0 structure (128x128 tile, 4 waves 2x2, 256 thr)
// + ONE change: double-buffered LDS with next-tile global_load_lds issued
// BEFORE the current tile's ds_read+MFMA (T3-minimum 2-phase, m248 recipe).
// __syncthreads() per K-tile is the single gate — its implicit
// vmcnt(0)+lgkmcnt(0) drain guarantees the prefetched tile landed and all
// reads of the buffer being overwritten next have completed. No inline asm,
// no raw barriers (R1-R3's 512-thread macro/asm variant hit an opaque
// ~1.1 GB scratch pathology three times; reverted to the known-good lane).
// 16B-chunk XOR swizzle (slot = g ^ (row&7)) on both staging (pre-swizzled
// global src, linear LDS dest) and ds_read_b128 fragment reads.
__global__ __launch_bounds__(256) void k_gemm_sumexp(
    const unsigned char* __restrict__ z1f, const unsigned char* __restrict__ z2f,
    float* __restrict__ P) {
    __shared__ __attribute__((aligned(16))) unsigned char As[2][128 * BK]; // 32 KB
    __shared__ __attribute__((aligned(16))) unsigned char Bs[2][128 * BK]; // 32 KB

    const int iT = blockIdx.y, jT = blockIdx.x;
    const int lane = threadIdx.x & 63, wave = threadIdx.x >> 6;
    const int wm = wave >> 1, wn = wave & 1;     // 2x2 wave grid
    const int ml = lane & 15, q = lane >> 4;     // MFMA lane decomposition
    const int i0 = iT * 128, j0 = jT * 128;

    // staging: one wave-issue = 1 KB = 8 rows x 128 B. lane l: row = l>>3,
    // LDS chunk slot = l&7, global chunk g = (l&7) ^ (row&7).
    const int srow = lane >> 3;                       // 0..7 within issue
    const int sg = ((lane & 7) ^ srow) * 16;          // swizzled global byte off

    // fragment-read slots for this lane (32 k-bytes [q*32, +32) of row ml)
    const int rs = ml & 7;
    const int slotL = ((2 * q) ^ rs) * 16;
    const int slotH = ((2 * q + 1) ^ rs) * 16;

    floatx4 acc[4][4];
    #pragma unroll
    for (int mt = 0; mt < 4; ++mt)
        #pragma unroll
        for (int nt = 0; nt < 4; ++nt)
            acc[mt][nt] = (floatx4){0.f, 0.f, 0.f, 0.f};

    // prologue: stage K-tile 0 into buffer 0
    #pragma unroll
    for (int c = 0; c < 4; ++c) {
        const int issue = wave * 4 + c;              // 0..15
        const int row = issue * 8 + srow;            // 0..127
        const unsigned char* gA = z1f + (size_t)(i0 + row) * DIM + sg;
        const unsigned char* gB = z2f + (size_t)(j0 + row) * DIM + sg;
        __builtin_amdgcn_global_load_lds(
            (const __attribute__((address_space(1))) void*)gA,
            (__attribute__((address_space(3))) void*)(&As[0][issue * 1024]), 16, 0, 0);
        __builtin_amdgcn_global_load_lds(
            (const __attribute__((address_space(1))) void*)gB,
            (__attribute__((address_space(3))) void*)(&Bs[0][issue * 1024]), 16, 0, 0);
    }
    __syncthreads();

    #pragma unroll
    for (int kt = 0; kt < 8; ++kt) {
        const int cur = kt & 1;
        // issue next tile's loads into the other buffer (flies during MFMA)
        if (kt < 7) {
            const int k0n = (kt + 1) * BK;
            #pragma unroll
            for (int c = 0; c < 4; ++c) {
                const int issue = wave * 4 + c;
                const int row = issue * 8 + srow;
                const unsigned char* gA = z1f + (size_t)(i0 + row) * DIM + k0n + sg;
                const unsigned char* gB = z2f + (size_t)(j0 + row) * DIM + k0n + sg;
                __builtin_amdgcn_global_load_lds(
                    (const __attribute__((address_space(1))) void*)gA,
                    (__attribute__((address_space(3))) void*)(&As[cur ^ 1][issue * 1024]),
                    16, 0, 0);
                __builtin_amdgcn_global_load_lds(
                    (const __attribute__((address_space(1))) void*)gB,
                    (__attribute__((address_space(3))) void*)(&Bs[cur ^ 1][issue * 1024]),
                    16, 0, 0);
            }
        }

        int8x af[4], bf[4];
        #pragma unroll
        for (int t = 0; t < 4; ++t) {
            const unsigned char* rowA = &As[cur][0] + (wm * 64 + t * 16 + ml) * BK;
            const unsigned char* rowB = &Bs[cur][0] + (wn * 64 + t * 16 + ml) * BK;
            int4x aL = *reinterpret_cast<const int4x*>(rowA + slotL);
            int4x aH = *reinterpret_cast<const int4x*>(rowA + slotH);
            int4x bLo = *reinterpret_cast<const int4x*>(rowB + slotL);
            int4x bHi = *reinterpret_cast<const int4x*>(rowB + slotH);
            af[t] = __builtin_shufflevector(aL, aH, 0, 1, 2, 3, 4, 5, 6, 7);
            bf[t] = __builtin_shufflevector(bLo, bHi, 0, 1, 2, 3, 4, 5, 6, 7);
        }
        #pragma unroll
        for (int mt = 0; mt < 4; ++mt)
            #pragma unroll
            for (int nt = 0; nt < 4; ++nt)
                acc[mt][nt] = __builtin_amdgcn_mfma_scale_f32_16x16x128_f8f6f4(
                    af[mt], bf[nt], acc[mt][nt],
                    0 /*fmt A = fp8*/, 0 /*fmt B = fp8*/,
                    0, 0x7F /*scale A = 1.0*/, 0, 0x7F /*scale B = 1.0*/);
        // single gate per K-tile: drains vmcnt (prefetched tile landed) and
        // orders buffer reuse across waves.
        __syncthreads();
    }

    // Epilogue. C/D layout: col=lane&15, row=q*4+reg. exp + row-sum over the
    // wave's 64 columns, butterfly across 16 ml-lanes; combine the two
    // wn-waves via LDS; one plain store per (jT, i).
    float vv[4][4];
    #pragma unroll
    for (int mt = 0; mt < 4; ++mt) {
        #pragma unroll
        for (int r = 0; r < 4; ++r) {
            float v = 0.f;
            #pragma unroll
            for (int nt = 0; nt < 4; ++nt)
                v += __builtin_amdgcn_exp2f(acc[mt][nt][r] * EXP_SCALE);
            v += __shfl_xor(v, 1, 64);
            v += __shfl_xor(v, 2, 64);
            v += __shfl_xor(v, 4, 64);
            v += __shfl_xor(v, 8, 64);
            vv[mt][r] = v;
        }
    }
    float* Pl = reinterpret_cast<float*>(&As[0][0]);  // reuse (all LDS reads done)
    if (wn == 1 && ml == 0) {
        #pragma unroll
        for (int mt = 0; mt < 4; ++mt)
            #pragma unroll
            for (int r = 0; r < 4; ++r)
                Pl[wm * 64 + mt * 16 + q * 4 + r] = vv[mt][r];
    }
    __syncthreads();
    if (wn == 0 && ml == 0) {
        #pragma unroll
        for (int mt = 0; mt < 4; ++mt)
            #pragma unroll
            for (int r = 0; r < 4; ++r) {
                const int ri = wm * 64 + mt * 16 + q * 4 + r;
                P[jT * N_ROWS + i0 + ri] = vv[mt][r] + Pl[ri];
            }
    }
}

// 32 blocks x 128 threads: one row per thread, coalesced P reads,
// block partial-sum -> atomicAdd into out[0] (zeroed by k_normalize).
__global__ __launch_bounds__(128) void k_finalize(
    const float* __restrict__ P, const float* __restrict__ diag,
    float* __restrict__ out) {
    const int t = threadIdx.x;
    const int i = blockIdx.x * 128 + t;
    float s = 0.f;
    #pragma unroll
    for (int jt = 0; jt < NJT; ++jt)
        s += P[jt * N_ROWS + i];
    float v = logf(s) - diag[i];
    #pragma unroll
    for (int m = 32; m >= 1; m >>= 1)
        v += __shfl_xor(v, m, 64);
    __shared__ float r[2];
    if ((t & 63) == 0) r[t >> 6] = v;
    __syncthreads();
    if (t == 0) atomicAdd(out, (r[0] + r[1]) * (1.0f / N_ROWS));
}

extern "C" void kernel_launch(void* const* d_in, const int* in_sizes, int n_in,
                              void* d_out, int out_size, void* d_ws, size_t ws_size,
                              hipStream_t stream) {
    const float* z1 = (const float*)d_in[0];
    const float* z2 = (const float*)d_in[1];

    char* ws = (char*)d_ws;
    unsigned char* z1f = (unsigned char*)ws;                                     // 4 MB
    unsigned char* z2f = (unsigned char*)(ws + (size_t)N_ROWS * DIM);            // 4 MB
    float* diag = (float*)(ws + (size_t)N_ROWS * DIM * 2);                       // 16 KB
    float* P = diag + N_ROWS;                                                    // 512 KB

    k_normalize<<<N_ROWS / 4, 256, 0, stream>>>(z1, z2, z1f, z2f, diag,
                                                (float*)d_out);
    k_gemm_sumexp<<<dim3(NJT, 32), 256, 0, stream>>>(z1f, z2f, P);
    k_finalize<<<32, 128, 0, stream>>>(P, diag, (float*)d_out);
}